// Round 8
// baseline (437.837 us; speedup 1.0000x reference)
//
#include <hip/hip_runtime.h>
#include <stdint.h>

#define NB  32     // B
#define NN  1024   // N
#define FIN 128
#define HH  64
#define CC  32
#define ZCAP 16
#define NITER 5

using short8  = __attribute__((ext_vector_type(8))) short;
using floatx4 = __attribute__((ext_vector_type(4))) float;

__device__ inline float b2f(unsigned short u) {
  union { uint32_t i; float f; } v; v.i = ((uint32_t)u) << 16; return v.f;
}
__device__ inline float b2f_lo(uint32_t w) {
  union { uint32_t i; float f; } v; v.i = w << 16; return v.f;
}
__device__ inline float b2f_hi(uint32_t w) {
  union { uint32_t i; float f; } v; v.i = w & 0xFFFF0000u; return v.f;
}
__device__ inline unsigned short f2b(float f) {
  union { uint32_t i; float f; } v; v.f = f;
  uint32_t r = v.i + 0x7FFFu + ((v.i >> 16) & 1u);
  return (unsigned short)(r >> 16);
}
__device__ inline floatx4 zf4() { floatx4 v = {0.f, 0.f, 0.f, 0.f}; return v; }

// ---------------------------------------------------------------------------
// k_wcvt: weight transposes to bf16 + zero d_out. 1 block.
// ---------------------------------------------------------------------------
__global__ __launch_bounds__(256) void k_wcvt(const float* __restrict__ Wg,
    const float* __restrict__ Wu, unsigned short* __restrict__ Wgt,
    unsigned short* __restrict__ Wut, float* __restrict__ out, int out_n) {
  const int t = threadIdx.x;
  for (int idx = t; idx < HH * FIN; idx += 256) {
    int hh = idx >> 7, f = idx & 127;
    Wgt[idx] = f2b(Wg[f * HH + hh]);
  }
  for (int idx = t; idx < CC * HH; idx += 256) {
    int c = idx >> 6, f = idx & 63;
    Wut[idx] = f2b(Wu[f * CC + c]);
  }
  for (int idx = t; idx < out_n; idx += 256) out[idx] = 0.f;
}

// ---------------------------------------------------------------------------
// k_bits: adj(int32) -> rowbits + dinv + zcnt=0. One wave/row, 4 int4 reps.
// ---------------------------------------------------------------------------
__global__ __launch_bounds__(256) void k_bits(const int* __restrict__ adj,
    uint32_t* __restrict__ rowbits, float* __restrict__ dinv,
    int* __restrict__ zcnt) {
  __shared__ uint32_t rw[4][32];
  const int t = threadIdx.x, g = t >> 6, lane = t & 63;
  if (lane < 32) rw[g][lane] = 0u;
  __syncthreads();
  const size_t row = (size_t)blockIdx.x * 4 + g;
  int s = 0;
  #pragma unroll
  for (int rep = 0; rep < 4; rep++) {
    int4 a = ((const int4*)(adj + row * NN))[rep * 64 + lane];
    int b0 = (a.x != 0), b1 = (a.y != 0), b2 = (a.z != 0), b3 = (a.w != 0);
    uint32_t nib = ((uint32_t)(b0 | (b1 << 1) | (b2 << 2) | (b3 << 3))) << ((lane & 7) * 4);
    atomicOr(&rw[g][rep * 8 + (lane >> 3)], nib);
    s += b0 + b1 + b2 + b3;
  }
  #pragma unroll
  for (int m = 1; m < 64; m <<= 1) s += __shfl_xor(s, m, 64);
  __syncthreads();
  if (lane < 32) rowbits[row * 32 + lane] = rw[g][lane];
  if (lane == 0) { dinv[row] = rsqrtf((float)s + 1.0f); zcnt[row] = 0; }
}

// ---------------------------------------------------------------------------
// k_cbits: colbits = bit-transpose(rowbits). grid = B*8 (half x jt), 256 thr
// ---------------------------------------------------------------------------
__global__ __launch_bounds__(256) void k_cbits(const uint32_t* __restrict__ rowbits,
    uint32_t* __restrict__ colbits) {
  __shared__ uint32_t rbL[512 * 32];   // 64 KB
  const int bid = blockIdx.x;
  const int b = bid >> 3, half = (bid >> 2) & 1, jt = bid & 3;
  const int t = threadIdx.x;
  const uint32_t* src = rowbits + ((size_t)b * NN + half * 512) * 32;
  for (int idx = t; idx < 512 * 32; idx += 256) rbL[idx] = src[idx];
  __syncthreads();
  const int j = jt * 256 + t, jw = j >> 5, jb = j & 31;
  uint32_t out[16];
  for (int w = 0; w < 16; w++) {
    uint32_t acc = 0;
    #pragma unroll
    for (int r = 0; r < 32; r++)
      acc |= ((rbL[(w * 32 + r) * 32 + jw] >> jb) & 1u) << r;
    out[w] = acc;
  }
  uint4* dst = (uint4*)(colbits + ((size_t)b * NN + j) * 32 + half * 16);
  #pragma unroll
  for (int x = 0; x < 4; x++) {
    uint4 v; v.x = out[4*x]; v.y = out[4*x+1]; v.z = out[4*x+2]; v.w = out[4*x+3];
    dst[x] = v;
  }
}

// ---------------------------------------------------------------------------
// k_xw (MFMA): xs[n][h] = bf16(dinv_n * (x[n,:] @ Wg)); xst[h][n] transposed.
// ---------------------------------------------------------------------------
__global__ __launch_bounds__(256) void k_xw(const float* __restrict__ x,
    const unsigned short* __restrict__ Wgt, const float* __restrict__ dinv,
    unsigned short* __restrict__ xs, unsigned short* __restrict__ xst) {
  const int bid = blockIdx.x;
  const int b = bid >> 4;
  const int m0 = (bid & 15) * 64;
  const int t = threadIdx.x, wv = t >> 6, lane = t & 63, l15 = lane & 15, q = lane >> 4;
  const int mb = m0 + wv * 16;
  floatx4 acc[4];
  #pragma unroll
  for (int u = 0; u < 4; u++) acc[u] = zf4();
  #pragma unroll
  for (int k0 = 0; k0 < FIN; k0 += 32) {
    const float4* xp = (const float4*)(x + ((size_t)b * NN + mb + l15) * FIN + k0 + q * 8);
    float4 a0 = xp[0], a1 = xp[1];
    short8 af;
    af[0] = (short)f2b(a0.x); af[1] = (short)f2b(a0.y);
    af[2] = (short)f2b(a0.z); af[3] = (short)f2b(a0.w);
    af[4] = (short)f2b(a1.x); af[5] = (short)f2b(a1.y);
    af[6] = (short)f2b(a1.z); af[7] = (short)f2b(a1.w);
    #pragma unroll
    for (int u = 0; u < 4; u++) {
      short8 bf = *(const short8*)(Wgt + (u * 16 + l15) * FIN + k0 + q * 8);
      acc[u] = __builtin_amdgcn_mfma_f32_16x16x32_bf16(af, bf, acc[u], 0, 0, 0);
    }
  }
  #pragma unroll
  for (int r = 0; r < 4; r++) {
    const int i = mb + q * 4 + r;
    const float dv = dinv[b * NN + i];
    #pragma unroll
    for (int u = 0; u < 4; u++) {
      const int c = u * 16 + l15;
      unsigned short bv = f2b(dv * acc[u][r]);
      xs[((size_t)b * NN + i) * HH + c] = bv;
      xst[((size_t)b * HH + c) * NN + i] = bv;
    }
  }
}

// ---------------------------------------------------------------------------
// k_gcnun: h = relu(dinv_i*(A@xs + xs_i) + bg); fused e2 and unary = h@Wu+bu.
// grid = B*16, 256 thr
// ---------------------------------------------------------------------------
__global__ __launch_bounds__(256) void k_gcnun(const uint32_t* __restrict__ rowbits,
    const unsigned short* __restrict__ xst, const unsigned short* __restrict__ xs,
    const float* __restrict__ dinv, const float* __restrict__ bg,
    const float* __restrict__ means, const float* __restrict__ scales,
    const unsigned short* __restrict__ Wut, const float* __restrict__ bu,
    float* __restrict__ h, float* __restrict__ e2, float* __restrict__ unary) {
  __shared__ unsigned short hsh[4][16][72];   // 9 KB, wave-private tiles
  const int bid = blockIdx.x;
  const int b = bid >> 4;
  const int m0 = (bid & 15) * 64;
  const int t = threadIdx.x, wv = t >> 6, lane = t & 63, l15 = lane & 15, q = lane >> 4;
  const int mb = m0 + wv * 16;
  floatx4 acc[4];
  #pragma unroll
  for (int u = 0; u < 4; u++) acc[u] = zf4();
  const uint32_t* rbrow = rowbits + ((size_t)b * NN + mb + l15) * 32;
  for (int k0 = 0; k0 < NN; k0 += 32) {
    uint32_t sh = rbrow[k0 >> 5] >> (q * 8);
    short8 af;
    #pragma unroll
    for (int jj = 0; jj < 8; jj++)
      af[jj] = (short)(((sh >> jj) & 1u) ? 0x3F80 : 0);
    #pragma unroll
    for (int u = 0; u < 4; u++) {
      short8 bf = *(const short8*)(xst + ((size_t)b * HH + u * 16 + l15) * NN + k0 + q * 8);
      acc[u] = __builtin_amdgcn_mfma_f32_16x16x32_bf16(af, bf, acc[u], 0, 0, 0);
    }
  }
  float bgc[4], mn0[4], mn1[4], is0[4], is1[4];
  #pragma unroll
  for (int u = 0; u < 4; u++) {
    const int c = u * 16 + l15;
    bgc[u] = bg[c];
    mn0[u] = means[c];        is0[u] = 1.0f / scales[c];
    mn1[u] = means[HH + c];   is1[u] = 1.0f / scales[HH + c];
  }
  #pragma unroll
  for (int r = 0; r < 4; r++) {
    const int i = mb + q * 4 + r;
    const float dv = dinv[b * NN + i];
    float dd0 = 0.f, dd1 = 0.f;
    #pragma unroll
    for (int u = 0; u < 4; u++) {
      const int c = u * 16 + l15;
      float xsv = b2f(xs[((size_t)b * NN + i) * HH + c]);
      float v = dv * (acc[u][r] + xsv) + bgc[u];
      v = v > 0.f ? v : 0.f;
      h[((size_t)b * NN + i) * HH + c] = v;
      unsigned short hb = f2b(v);
      hsh[wv][q * 4 + r][c] = hb;
      float vb = b2f(hb);
      float t0 = (vb - mn0[u]) * is0[u]; dd0 += t0 * t0;
      float t1 = (vb - mn1[u]) * is1[u]; dd1 += t1 * t1;
    }
    #pragma unroll
    for (int m = 1; m < 16; m <<= 1) {
      dd0 += __shfl_xor(dd0, m, 64);
      dd1 += __shfl_xor(dd1, m, 64);
    }
    if (l15 == 0) {
      e2[((size_t)b * NN + i) * 2 + 0] = __expf(-dd0);
      e2[((size_t)b * NN + i) * 2 + 1] = __expf(-dd1);
    }
  }
  floatx4 uacc[2];
  uacc[0] = zf4(); uacc[1] = zf4();
  #pragma unroll
  for (int k0 = 0; k0 < HH; k0 += 32) {
    short8 af = *(const short8*)&hsh[wv][l15][k0 + q * 8];
    #pragma unroll
    for (int u = 0; u < 2; u++) {
      short8 bf = *(const short8*)(Wut + (u * 16 + l15) * HH + k0 + q * 8);
      uacc[u] = __builtin_amdgcn_mfma_f32_16x16x32_bf16(af, bf, uacc[u], 0, 0, 0);
    }
  }
  const float bu0 = bu[l15], bu1 = bu[16 + l15];
  #pragma unroll
  for (int r = 0; r < 4; r++) {
    const int i = mb + q * 4 + r;
    unary[((size_t)b * NN + i) * CC + l15] = uacc[0][r] + bu0;
    unary[((size_t)b * NN + i) * CC + 16 + l15] = uacc[1][r] + bu1;
  }
}

// ---------------------------------------------------------------------------
// k_zscan: rows of (A^2)==0 -> zcnt/zidx. grid = B*8
// ---------------------------------------------------------------------------
__global__ __launch_bounds__(256) void k_zscan(const uint32_t* __restrict__ rowbits,
    const uint32_t* __restrict__ colbits, int* __restrict__ zcnt,
    int* __restrict__ zidx) {
  __shared__ uint32_t rwL[128 * 32];   // 16 KB
  const int bid = blockIdx.x;
  const int b = bid >> 3, it = bid & 7;
  const int i0 = it * 128;
  const int t = threadIdx.x;
  #pragma unroll
  for (int x = 0; x < 16; x++)
    rwL[x * 256 + t] = rowbits[((size_t)b * NN + i0) * 32 + x * 256 + t];
  __syncthreads();
  for (int jc = 0; jc < 4; jc++) {
    const int j = jc * 256 + t;
    uint32_t cb[32];
    const uint4* cbp = (const uint4*)(colbits + ((size_t)b * NN + j) * 32);
    #pragma unroll
    for (int x = 0; x < 8; x++) {
      uint4 v = cbp[x];
      cb[4*x] = v.x; cb[4*x+1] = v.y; cb[4*x+2] = v.z; cb[4*x+3] = v.w;
    }
    for (int i = 0; i < 128; i++) {
      uint32_t m = 0;
      for (int w = 0; w < 32; w++) {
        m |= rwL[i * 32 + w] & cb[w];
        if (__all(m != 0)) break;
      }
      if (m == 0) {
        int old = atomicAdd(&zcnt[b * NN + i0 + i], 1);
        if (old < ZCAP) zidx[(size_t)(b * NN + i0 + i) * ZCAP + old] = j;
      }
    }
  }
}

// ---------------------------------------------------------------------------
// k_crf1: ONE launch for init + all 5 CRF iterations + x_pooled partials.
// grid = B*4 = 128 blocks, 256 thr. Each block redundantly simulates its
// whole batch (Q bf16-packed in LDS, stride 17 = conflict-free), writes only
// its 256-node shard of qtb, plus x_pooled partial for its shard.
// ---------------------------------------------------------------------------
__global__ __launch_bounds__(256) void k_crf1(const float* __restrict__ unary,
    const float* __restrict__ e2g, const float* __restrict__ kwp,
    const float* __restrict__ mu, const uint32_t* __restrict__ rowbits,
    const uint32_t* __restrict__ colbits, const int* __restrict__ zcnt,
    const int* __restrict__ zidx, const float* __restrict__ h,
    unsigned short* __restrict__ qtb, float* __restrict__ out) {
  __shared__ uint32_t QLu[NN * 17];    // 69632 B
  __shared__ float eL[NN * 2];         // 8192 B
  __shared__ float muL[CC * CC];       // 4096 B
  __shared__ float part[4][64];        // 1024 B
  __shared__ float Tf[64];             // 256 B
  __shared__ float S[64];              // 256 B
  const int bid = blockIdx.x;
  const int b = bid >> 2, seg = bid & 3;
  const int t = threadIdx.x;
  const float kw0 = kwp[0], kw1 = kwp[1];
  for (int i = t; i < CC * CC; i += 256) muL[i] = mu[i];
  // init: e2 into LDS; Q0 = softmax(unary) for ALL nodes (4 per thread)
  for (int n = t; n < NN; n += 256) {
    float2 ev = ((const float2*)(e2g + ((size_t)b * NN + n) * 2))[0];
    eL[n * 2] = ev.x; eL[n * 2 + 1] = ev.y;
    float lg[CC];
    const float4* ur = (const float4*)(unary + ((size_t)b * NN + n) * CC);
    #pragma unroll
    for (int c4 = 0; c4 < 8; c4++) {
      float4 v = ur[c4];
      lg[c4*4] = v.x; lg[c4*4+1] = v.y; lg[c4*4+2] = v.z; lg[c4*4+3] = v.w;
    }
    float mx = lg[0];
    #pragma unroll
    for (int c = 1; c < CC; c++) mx = fmaxf(mx, lg[c]);
    float s = 0.f;
    #pragma unroll
    for (int c = 0; c < CC; c++) { lg[c] = __expf(lg[c] - mx); s += lg[c]; }
    float inv = 1.f / s;
    #pragma unroll
    for (int d2 = 0; d2 < 16; d2++)
      QLu[n * 17 + d2] = (uint32_t)f2b(lg[2*d2] * inv)
                       | ((uint32_t)f2b(lg[2*d2+1] * inv) << 16);
  }
  __syncthreads();
  const int kd = t & 63, dd = t & 31, kk = (t >> 5) & 1, sub = t >> 6;
  for (int it = 0; it < NITER; it++) {
    // --- T[k][d] = sum_j e_jk * Q[j][d] (each thread: one (k,d), 256 j) ---
    float s = 0.f;
    for (int jj = 0; jj < 256; jj++) {
      const int j = sub * 256 + jj;
      const float ej = eL[j * 2 + kk];
      const uint32_t w = QLu[j * 17 + (dd >> 1)];
      s += ej * ((dd & 1) ? b2f_hi(w) : b2f_lo(w));
    }
    part[sub][kd] = s;
    __syncthreads();
    if (t < 64) Tf[t] = part[0][t] + part[1][t] + part[2][t] + part[3][t];
    __syncthreads();
    if (t < 64) {
      const int k = t >> 5, c = t & 31;
      float ss = 0.f;
      #pragma unroll 8
      for (int d = 0; d < CC; d++) ss += Tf[k * 32 + d] * muL[d * 32 + c];
      S[t] = ((k == 0) ? kw0 : kw1) * ss;
    }
    __syncthreads();
    // --- update ALL nodes (4 per thread), new Q staged in registers ---
    uint32_t newq[4][16];
    #pragma unroll
    for (int rep = 0; rep < 4; rep++) {
      const int n = rep * 256 + t;
      const float e0 = eL[n * 2], e1 = eL[n * 2 + 1];
      float lg[CC];
      {
        const float4* ur = (const float4*)(unary + ((size_t)b * NN + n) * CC);
        const float4* S0 = (const float4*)S;
        const float4* S1 = (const float4*)(S + 32);
        #pragma unroll
        for (int c4 = 0; c4 < 8; c4++) {
          float4 uv = ur[c4], s0 = S0[c4], s1 = S1[c4];
          lg[c4*4]   = uv.x + e0 * s0.x + e1 * s1.x;
          lg[c4*4+1] = uv.y + e0 * s0.y + e1 * s1.y;
          lg[c4*4+2] = uv.z + e0 * s0.z + e1 * s1.z;
          lg[c4*4+3] = uv.w + e0 * s0.w + e1 * s1.w;
        }
      }
      const int zc = zcnt[b * NN + n];
      if (zc > 0) {
        if (zc <= ZCAP) {
          for (int z = 0; z < zc; z++) {
            const int j = zidx[(size_t)(b * NN + n) * ZCAP + z];
            const float w = kw0 * e0 * eL[j * 2] + kw1 * e1 * eL[j * 2 + 1];
            for (int d2 = 0; d2 < 16; d2++) {
              const uint32_t wq = QLu[j * 17 + d2];
              const float w0 = w * b2f_lo(wq), w1 = w * b2f_hi(wq);
              #pragma unroll 8
              for (int c = 0; c < CC; c++)
                lg[c] -= w0 * muL[(2*d2) * 32 + c] + w1 * muL[(2*d2+1) * 32 + c];
            }
          }
        } else {  // dense fallback (never triggers for this input)
          const uint32_t* rbi = rowbits + ((size_t)b * NN + n) * 32;
          for (int j = 0; j < NN; j++) {
            uint32_t m = 0;
            const uint32_t* cbj = colbits + ((size_t)b * NN + j) * 32;
            for (int w32 = 0; w32 < 32; w32++) m |= rbi[w32] & cbj[w32];
            if (m == 0) {
              const float w = kw0 * e0 * eL[j * 2] + kw1 * e1 * eL[j * 2 + 1];
              for (int d2 = 0; d2 < 16; d2++) {
                const uint32_t wq = QLu[j * 17 + d2];
                const float w0 = w * b2f_lo(wq), w1 = w * b2f_hi(wq);
                #pragma unroll 8
                for (int c = 0; c < CC; c++)
                  lg[c] -= w0 * muL[(2*d2) * 32 + c] + w1 * muL[(2*d2+1) * 32 + c];
              }
            }
          }
        }
      }
      float mx = lg[0];
      #pragma unroll
      for (int c = 1; c < CC; c++) mx = fmaxf(mx, lg[c]);
      float ss = 0.f;
      #pragma unroll
      for (int c = 0; c < CC; c++) { lg[c] = __expf((lg[c] - mx) * 2.0f); ss += lg[c]; }
      const float inv = 1.f / ss;
      #pragma unroll
      for (int d2 = 0; d2 < 16; d2++)
        newq[rep][d2] = (uint32_t)f2b(lg[2*d2] * inv)
                      | ((uint32_t)f2b(lg[2*d2+1] * inv) << 16);
    }
    __syncthreads();   // all reads of old QLu complete
    #pragma unroll
    for (int rep = 0; rep < 4; rep++) {
      const int n = rep * 256 + t;
      #pragma unroll
      for (int d2 = 0; d2 < 16; d2++) QLu[n * 17 + d2] = newq[rep][d2];
    }
    __syncthreads();
  }
  // --- write own shard of qtb (bf16 [C][N]) ---
  {
    const int n = seg * 256 + t;
    #pragma unroll
    for (int d2 = 0; d2 < 16; d2++) {
      const uint32_t w = QLu[n * 17 + d2];
      qtb[((size_t)b * CC + 2*d2) * NN + n]     = (unsigned short)(w & 0xFFFFu);
      qtb[((size_t)b * CC + 2*d2 + 1) * NN + n] = (unsigned short)(w >> 16);
    }
  }
  // --- x_pooled partial for own shard: out[b,c,hh] += sum_j Q[j,c]*h[j,hh] ---
  {
    const int hh = t & 63, cg = t >> 6;
    float acc[8] = {0, 0, 0, 0, 0, 0, 0, 0};
    const int j0 = seg * 256;
    for (int jj = 0; jj < 256; jj++) {
      const int j = j0 + jj;
      const float hv = h[((size_t)b * NN + j) * HH + hh];
      #pragma unroll
      for (int w = 0; w < 4; w++) {
        const uint32_t q2 = QLu[j * 17 + cg * 4 + w];
        acc[2*w]     += b2f_lo(q2) * hv;
        acc[2*w + 1] += b2f_hi(q2) * hv;
      }
    }
    #pragma unroll
    for (int k = 0; k < 8; k++)
      atomicAdd(&out[((size_t)b * CC + cg * 8 + k) * HH + hh], acc[k]);
  }
}

// ---------------------------------------------------------------------------
// k_adjqp: adjQ = A @ Q (MFMA from rowbits + qtb), then immediately reduce
// adj_pooled[b,c,d] += sum_i Q[i,c]*adjQ[i,d] via LDS tiles. grid = B*16.
// ---------------------------------------------------------------------------
__global__ __launch_bounds__(256) void k_adjqp(const uint32_t* __restrict__ rowbits,
    const unsigned short* __restrict__ qtb, float* __restrict__ out) {
  __shared__ float adjL[64][33];   // 8448 B (pad 33 breaks bank conflicts)
  __shared__ float qL[64][32];     // 8192 B
  const int bid = blockIdx.x;
  const int b = bid >> 4;
  const int m0 = (bid & 15) * 64;
  const int t = threadIdx.x, wv = t >> 6, lane = t & 63, l15 = lane & 15, q = lane >> 4;
  const int mb = m0 + wv * 16;
  floatx4 acc[2];
  acc[0] = zf4(); acc[1] = zf4();
  const uint32_t* rbrow = rowbits + ((size_t)b * NN + mb + l15) * 32;
  for (int k0 = 0; k0 < NN; k0 += 32) {
    uint32_t sh = rbrow[k0 >> 5] >> (q * 8);
    short8 af;
    #pragma unroll
    for (int jj = 0; jj < 8; jj++)
      af[jj] = (short)(((sh >> jj) & 1u) ? 0x3F80 : 0);
    #pragma unroll
    for (int u = 0; u < 2; u++) {
      short8 bf = *(const short8*)(qtb + ((size_t)b * CC + u * 16 + l15) * NN + k0 + q * 8);
      acc[u] = __builtin_amdgcn_mfma_f32_16x16x32_bf16(af, bf, acc[u], 0, 0, 0);
    }
  }
  // stage adjQ tile + Q tile (coalesced i-major from qtb)
  #pragma unroll
  for (int r = 0; r < 4; r++)
    #pragma unroll
    for (int u = 0; u < 2; u++)
      adjL[wv * 16 + q * 4 + r][u * 16 + l15] = acc[u][r];
  #pragma unroll
  for (int x = 0; x < 8; x++) {
    const int idx = x * 256 + t;
    const int i = idx & 63, c = idx >> 6;
    qL[i][c] = b2f(qtb[((size_t)b * CC + c) * NN + m0 + i]);
  }
  __syncthreads();
  const int d = t & 31, cg = t >> 5;
  float a2[4] = {0, 0, 0, 0};
  for (int i = 0; i < 64; i++) {
    const float av = adjL[i][d];
    #pragma unroll
    for (int k = 0; k < 4; k++) a2[k] += qL[i][cg * 4 + k] * av;
  }
  #pragma unroll
  for (int k = 0; k < 4; k++)
    atomicAdd(&out[(size_t)NB * CC * HH + ((size_t)b * CC + cg * 4 + k) * CC + d], a2[k]);
}

// ---------------------------------------------------------------------------
extern "C" void kernel_launch(void* const* d_in, const int* in_sizes, int n_in,
                              void* d_out, int out_size, void* d_ws, size_t ws_size,
                              hipStream_t stream) {
  (void)in_sizes; (void)n_in; (void)out_size;
  const float* x      = (const float*)d_in[0];
  const int*   adj    = (const int*)d_in[1];
  const float* Wg     = (const float*)d_in[2];
  const float* bg     = (const float*)d_in[3];
  const float* Wu     = (const float*)d_in[4];
  const float* bu     = (const float*)d_in[5];
  const float* means  = (const float*)d_in[6];
  const float* scales = (const float*)d_in[7];
  const float* kw     = (const float*)d_in[8];
  const float* mu     = (const float*)d_in[9];

  char* ws = (char*)d_ws;
  size_t off = 0;
  auto alloc = [&](size_t bytes) { char* p = ws + off; off += (bytes + 255) & ~(size_t)255; return p; };
  uint32_t*       rbits = (uint32_t*)alloc((size_t)NB * NN * 32 * 4);
  uint32_t*       cbits = (uint32_t*)alloc((size_t)NB * NN * 32 * 4);
  float*          dinv  = (float*)alloc((size_t)NB * NN * 4);
  unsigned short* Wgt   = (unsigned short*)alloc((size_t)HH * FIN * 2);
  unsigned short* Wut   = (unsigned short*)alloc((size_t)CC * HH * 2);
  unsigned short* xs    = (unsigned short*)alloc((size_t)NB * NN * HH * 2);
  unsigned short* xst   = (unsigned short*)alloc((size_t)NB * HH * NN * 2);
  float*          h     = (float*)alloc((size_t)NB * NN * HH * 4);
  float*          e2    = (float*)alloc((size_t)NB * NN * 2 * 4);
  float*          unary = (float*)alloc((size_t)NB * NN * CC * 4);
  int*            zcnt  = (int*)alloc((size_t)NB * NN * 4);
  int*            zidx  = (int*)alloc((size_t)NB * NN * ZCAP * 4);
  unsigned short* qtb   = (unsigned short*)alloc((size_t)NB * CC * NN * 2);
  if (off > ws_size) return;

  float* out = (float*)d_out;
  const int out_n = NB * CC * (HH + CC);

  k_wcvt <<<1, 256, 0, stream>>>(Wg, Wu, Wgt, Wut, out, out_n);
  k_bits <<<NB * NN / 4, 256, 0, stream>>>(adj, rbits, dinv, zcnt);
  k_cbits<<<NB * 8, 256, 0, stream>>>(rbits, cbits);
  k_zscan<<<NB * 8, 256, 0, stream>>>(rbits, cbits, zcnt, zidx);
  k_xw   <<<NB * 16, 256, 0, stream>>>(x, Wgt, dinv, xs, xst);
  k_gcnun<<<NB * 16, 256, 0, stream>>>(rbits, xst, xs, dinv, bg, means, scales,
                                       Wut, bu, h, e2, unary);
  k_crf1 <<<NB * 4, 256, 0, stream>>>(unary, e2, kw, mu, rbits, cbits,
                                      zcnt, zidx, h, qtb, out);
  k_adjqp<<<NB * 16, 256, 0, stream>>>(rbits, qtb, out);
}

// Round 9
// 419.132 us; speedup vs baseline: 1.0446x; 1.0446x over previous
//
#include <hip/hip_runtime.h>
#include <stdint.h>

#define NB  32     // B
#define NN  1024   // N
#define FIN 128
#define HH  64
#define CC  32
#define ZCAP 16
#define NITER 5

using short8  = __attribute__((ext_vector_type(8))) short;
using floatx4 = __attribute__((ext_vector_type(4))) float;

__device__ inline float b2f(unsigned short u) {
  union { uint32_t i; float f; } v; v.i = ((uint32_t)u) << 16; return v.f;
}
__device__ inline float b2f_lo(uint32_t w) {
  union { uint32_t i; float f; } v; v.i = w << 16; return v.f;
}
__device__ inline float b2f_hi(uint32_t w) {
  union { uint32_t i; float f; } v; v.i = w & 0xFFFF0000u; return v.f;
}
__device__ inline unsigned short f2b(float f) {
  union { uint32_t i; float f; } v; v.f = f;
  uint32_t r = v.i + 0x7FFFu + ((v.i >> 16) & 1u);
  return (unsigned short)(r >> 16);
}
__device__ inline floatx4 zf4() { floatx4 v = {0.f, 0.f, 0.f, 0.f}; return v; }

// ---------------------------------------------------------------------------
// k_wcvt: weight transposes to bf16 + zero d_out. 1 block.
// ---------------------------------------------------------------------------
__global__ __launch_bounds__(256) void k_wcvt(const float* __restrict__ Wg,
    const float* __restrict__ Wu, unsigned short* __restrict__ Wgt,
    unsigned short* __restrict__ Wut, float* __restrict__ out, int out_n) {
  const int t = threadIdx.x;
  for (int idx = t; idx < HH * FIN; idx += 256) {
    int hh = idx >> 7, f = idx & 127;
    Wgt[idx] = f2b(Wg[f * HH + hh]);
  }
  for (int idx = t; idx < CC * HH; idx += 256) {
    int c = idx >> 6, f = idx & 63;
    Wut[idx] = f2b(Wu[f * CC + c]);
  }
  for (int idx = t; idx < out_n; idx += 256) out[idx] = 0.f;
}

// ---------------------------------------------------------------------------
// k_bits: adj(int32) -> rowbits + dinv + zcnt=0. One wave/row, 4 int4 reps.
// ---------------------------------------------------------------------------
__global__ __launch_bounds__(256) void k_bits(const int* __restrict__ adj,
    uint32_t* __restrict__ rowbits, float* __restrict__ dinv,
    int* __restrict__ zcnt) {
  __shared__ uint32_t rw[4][32];
  const int t = threadIdx.x, g = t >> 6, lane = t & 63;
  if (lane < 32) rw[g][lane] = 0u;
  __syncthreads();
  const size_t row = (size_t)blockIdx.x * 4 + g;
  int s = 0;
  #pragma unroll
  for (int rep = 0; rep < 4; rep++) {
    int4 a = ((const int4*)(adj + row * NN))[rep * 64 + lane];
    int b0 = (a.x != 0), b1 = (a.y != 0), b2 = (a.z != 0), b3 = (a.w != 0);
    uint32_t nib = ((uint32_t)(b0 | (b1 << 1) | (b2 << 2) | (b3 << 3))) << ((lane & 7) * 4);
    atomicOr(&rw[g][rep * 8 + (lane >> 3)], nib);
    s += b0 + b1 + b2 + b3;
  }
  #pragma unroll
  for (int m = 1; m < 64; m <<= 1) s += __shfl_xor(s, m, 64);
  __syncthreads();
  if (lane < 32) rowbits[row * 32 + lane] = rw[g][lane];
  if (lane == 0) { dinv[row] = rsqrtf((float)s + 1.0f); zcnt[row] = 0; }
}

// ---------------------------------------------------------------------------
// k_cbits: colbits = bit-transpose(rowbits). grid = B*8 (half x jt), 256 thr
// ---------------------------------------------------------------------------
__global__ __launch_bounds__(256) void k_cbits(const uint32_t* __restrict__ rowbits,
    uint32_t* __restrict__ colbits) {
  __shared__ uint32_t rbL[512 * 32];   // 64 KB
  const int bid = blockIdx.x;
  const int b = bid >> 3, half = (bid >> 2) & 1, jt = bid & 3;
  const int t = threadIdx.x;
  const uint32_t* src = rowbits + ((size_t)b * NN + half * 512) * 32;
  for (int idx = t; idx < 512 * 32; idx += 256) rbL[idx] = src[idx];
  __syncthreads();
  const int j = jt * 256 + t, jw = j >> 5, jb = j & 31;
  uint32_t out[16];
  for (int w = 0; w < 16; w++) {
    uint32_t acc = 0;
    #pragma unroll
    for (int r = 0; r < 32; r++)
      acc |= ((rbL[(w * 32 + r) * 32 + jw] >> jb) & 1u) << r;
    out[w] = acc;
  }
  uint4* dst = (uint4*)(colbits + ((size_t)b * NN + j) * 32 + half * 16);
  #pragma unroll
  for (int x = 0; x < 4; x++) {
    uint4 v; v.x = out[4*x]; v.y = out[4*x+1]; v.z = out[4*x+2]; v.w = out[4*x+3];
    dst[x] = v;
  }
}

// ---------------------------------------------------------------------------
// k_xw (MFMA): xs[n][h] = bf16(dinv_n * (x[n,:] @ Wg)); xst[h][n] transposed.
// ---------------------------------------------------------------------------
__global__ __launch_bounds__(256) void k_xw(const float* __restrict__ x,
    const unsigned short* __restrict__ Wgt, const float* __restrict__ dinv,
    unsigned short* __restrict__ xs, unsigned short* __restrict__ xst) {
  const int bid = blockIdx.x;
  const int b = bid >> 4;
  const int m0 = (bid & 15) * 64;
  const int t = threadIdx.x, wv = t >> 6, lane = t & 63, l15 = lane & 15, q = lane >> 4;
  const int mb = m0 + wv * 16;
  floatx4 acc[4];
  #pragma unroll
  for (int u = 0; u < 4; u++) acc[u] = zf4();
  #pragma unroll
  for (int k0 = 0; k0 < FIN; k0 += 32) {
    const float4* xp = (const float4*)(x + ((size_t)b * NN + mb + l15) * FIN + k0 + q * 8);
    float4 a0 = xp[0], a1 = xp[1];
    short8 af;
    af[0] = (short)f2b(a0.x); af[1] = (short)f2b(a0.y);
    af[2] = (short)f2b(a0.z); af[3] = (short)f2b(a0.w);
    af[4] = (short)f2b(a1.x); af[5] = (short)f2b(a1.y);
    af[6] = (short)f2b(a1.z); af[7] = (short)f2b(a1.w);
    #pragma unroll
    for (int u = 0; u < 4; u++) {
      short8 bf = *(const short8*)(Wgt + (u * 16 + l15) * FIN + k0 + q * 8);
      acc[u] = __builtin_amdgcn_mfma_f32_16x16x32_bf16(af, bf, acc[u], 0, 0, 0);
    }
  }
  #pragma unroll
  for (int r = 0; r < 4; r++) {
    const int i = mb + q * 4 + r;
    const float dv = dinv[b * NN + i];
    #pragma unroll
    for (int u = 0; u < 4; u++) {
      const int c = u * 16 + l15;
      unsigned short bv = f2b(dv * acc[u][r]);
      xs[((size_t)b * NN + i) * HH + c] = bv;
      xst[((size_t)b * HH + c) * NN + i] = bv;
    }
  }
}

// ---------------------------------------------------------------------------
// k_gcnun: h = relu(dinv_i*(A@xs + xs_i) + bg); fused e2, unary = h@Wu+bu,
// Q0 = softmax(unary) (bf16 row-major) and Tpart0 (16 partials/batch).
// grid = B*16, 256 thr
// ---------------------------------------------------------------------------
__global__ __launch_bounds__(256) void k_gcnun(const uint32_t* __restrict__ rowbits,
    const unsigned short* __restrict__ xst, const unsigned short* __restrict__ xs,
    const float* __restrict__ dinv, const float* __restrict__ bg,
    const float* __restrict__ means, const float* __restrict__ scales,
    const unsigned short* __restrict__ Wut, const float* __restrict__ bu,
    float* __restrict__ h, float* __restrict__ e2, float* __restrict__ unary,
    unsigned short* __restrict__ Q0, float* __restrict__ Tp0) {
  __shared__ unsigned short hsh[4][16][72];   // 9 KB
  __shared__ float Qs0[64][33];               // 8.4 KB
  __shared__ float es0[64][2];
  const int bid = blockIdx.x;
  const int b = bid >> 4, blk = bid & 15;
  const int m0 = blk * 64;
  const int t = threadIdx.x, wv = t >> 6, lane = t & 63, l15 = lane & 15, q = lane >> 4;
  const int mb = m0 + wv * 16;
  floatx4 acc[4];
  #pragma unroll
  for (int u = 0; u < 4; u++) acc[u] = zf4();
  const uint32_t* rbrow = rowbits + ((size_t)b * NN + mb + l15) * 32;
  for (int k0 = 0; k0 < NN; k0 += 32) {
    uint32_t sh = rbrow[k0 >> 5] >> (q * 8);
    short8 af;
    #pragma unroll
    for (int jj = 0; jj < 8; jj++)
      af[jj] = (short)(((sh >> jj) & 1u) ? 0x3F80 : 0);
    #pragma unroll
    for (int u = 0; u < 4; u++) {
      short8 bf = *(const short8*)(xst + ((size_t)b * HH + u * 16 + l15) * NN + k0 + q * 8);
      acc[u] = __builtin_amdgcn_mfma_f32_16x16x32_bf16(af, bf, acc[u], 0, 0, 0);
    }
  }
  float bgc[4], mn0[4], mn1[4], is0[4], is1[4];
  #pragma unroll
  for (int u = 0; u < 4; u++) {
    const int c = u * 16 + l15;
    bgc[u] = bg[c];
    mn0[u] = means[c];        is0[u] = 1.0f / scales[c];
    mn1[u] = means[HH + c];   is1[u] = 1.0f / scales[HH + c];
  }
  #pragma unroll
  for (int r = 0; r < 4; r++) {
    const int i = mb + q * 4 + r;
    const float dv = dinv[b * NN + i];
    float dd0 = 0.f, dd1 = 0.f;
    #pragma unroll
    for (int u = 0; u < 4; u++) {
      const int c = u * 16 + l15;
      float xsv = b2f(xs[((size_t)b * NN + i) * HH + c]);
      float v = dv * (acc[u][r] + xsv) + bgc[u];
      v = v > 0.f ? v : 0.f;
      h[((size_t)b * NN + i) * HH + c] = v;
      unsigned short hb = f2b(v);
      hsh[wv][q * 4 + r][c] = hb;
      float vb = b2f(hb);
      float t0 = (vb - mn0[u]) * is0[u]; dd0 += t0 * t0;
      float t1 = (vb - mn1[u]) * is1[u]; dd1 += t1 * t1;
    }
    #pragma unroll
    for (int m = 1; m < 16; m <<= 1) {
      dd0 += __shfl_xor(dd0, m, 64);
      dd1 += __shfl_xor(dd1, m, 64);
    }
    if (l15 == 0) {
      float ev0 = __expf(-dd0), ev1 = __expf(-dd1);
      e2[((size_t)b * NN + i) * 2 + 0] = ev0;
      e2[((size_t)b * NN + i) * 2 + 1] = ev1;
      es0[wv * 16 + q * 4 + r][0] = ev0;
      es0[wv * 16 + q * 4 + r][1] = ev1;
    }
  }
  floatx4 uacc[2];
  uacc[0] = zf4(); uacc[1] = zf4();
  #pragma unroll
  for (int k0 = 0; k0 < HH; k0 += 32) {
    short8 af = *(const short8*)&hsh[wv][l15][k0 + q * 8];
    #pragma unroll
    for (int u = 0; u < 2; u++) {
      short8 bf = *(const short8*)(Wut + (u * 16 + l15) * HH + k0 + q * 8);
      uacc[u] = __builtin_amdgcn_mfma_f32_16x16x32_bf16(af, bf, uacc[u], 0, 0, 0);
    }
  }
  const float bu0 = bu[l15], bu1 = bu[16 + l15];
  #pragma unroll
  for (int r = 0; r < 4; r++) {
    const int i = mb + q * 4 + r;
    const int iloc = wv * 16 + q * 4 + r;
    float a0 = uacc[0][r] + bu0;
    float a1 = uacc[1][r] + bu1;
    unary[((size_t)b * NN + i) * CC + l15] = a0;
    unary[((size_t)b * NN + i) * CC + 16 + l15] = a1;
    // Q0 = softmax over 32 cols spread across 16 lanes x 2 regs
    float mx = fmaxf(a0, a1);
    #pragma unroll
    for (int m = 1; m < 16; m <<= 1) mx = fmaxf(mx, __shfl_xor(mx, m, 64));
    float x0 = __expf(a0 - mx), x1 = __expf(a1 - mx);
    float s = x0 + x1;
    #pragma unroll
    for (int m = 1; m < 16; m <<= 1) s += __shfl_xor(s, m, 64);
    float inv = 1.f / s;
    float q0v = x0 * inv, q1v = x1 * inv;
    Q0[((size_t)b * NN + i) * CC + l15] = f2b(q0v);
    Q0[((size_t)b * NN + i) * CC + 16 + l15] = f2b(q1v);
    Qs0[iloc][l15] = q0v;
    Qs0[iloc][16 + l15] = q1v;
  }
  __syncthreads();
  if (t < 64) {   // Tpart0[k][d] = sum_{i<64} e_ik * Q0[i][d]
    const int k = t >> 5, d = t & 31;
    float s = 0.f;
    #pragma unroll 8
    for (int i = 0; i < 64; i++) s += es0[i][k] * Qs0[i][d];
    Tp0[((size_t)b * 16 + blk) * 64 + t] = s;
  }
}

// ---------------------------------------------------------------------------
// k_zscan: rows of (A^2)==0 -> zcnt/zidx. grid = B*8
// ---------------------------------------------------------------------------
__global__ __launch_bounds__(256) void k_zscan(const uint32_t* __restrict__ rowbits,
    const uint32_t* __restrict__ colbits, int* __restrict__ zcnt,
    int* __restrict__ zidx) {
  __shared__ uint32_t rwL[128 * 32];   // 16 KB
  const int bid = blockIdx.x;
  const int b = bid >> 3, it = bid & 7;
  const int i0 = it * 128;
  const int t = threadIdx.x;
  #pragma unroll
  for (int x = 0; x < 16; x++)
    rwL[x * 256 + t] = rowbits[((size_t)b * NN + i0) * 32 + x * 256 + t];
  __syncthreads();
  for (int jc = 0; jc < 4; jc++) {
    const int j = jc * 256 + t;
    uint32_t cb[32];
    const uint4* cbp = (const uint4*)(colbits + ((size_t)b * NN + j) * 32);
    #pragma unroll
    for (int x = 0; x < 8; x++) {
      uint4 v = cbp[x];
      cb[4*x] = v.x; cb[4*x+1] = v.y; cb[4*x+2] = v.z; cb[4*x+3] = v.w;
    }
    for (int i = 0; i < 128; i++) {
      uint32_t m = 0;
      for (int w = 0; w < 32; w++) {
        m |= rwL[i * 32 + w] & cb[w];
        if (__all(m != 0)) break;
      }
      if (m == 0) {
        int old = atomicAdd(&zcnt[b * NN + i0 + i], 1);
        if (old < ZCAP) zidx[(size_t)(b * NN + i0 + i) * ZCAP + old] = j;
      }
    }
  }
}

// ---------------------------------------------------------------------------
// k_supd2: one CRF iteration. grid = B*4, 256 thr, 1 node/thread.
// Sums npart T-partials -> S; update own 256 nodes; writes own T-partial for
// next iter (from fresh Q, LDS-staged). Last iter: qtb (c-major) + x_pooled.
// ---------------------------------------------------------------------------
__global__ __launch_bounds__(256) void k_supd2(const float* __restrict__ unary,
    const float* __restrict__ e2g, const float* __restrict__ TpIn, int npart,
    const float* __restrict__ mu, const float* __restrict__ kwp,
    const int* __restrict__ zcnt, const int* __restrict__ zidx,
    const unsigned short* __restrict__ Qprev, unsigned short* __restrict__ Qnext,
    float* __restrict__ TpOut, const uint32_t* __restrict__ rowbits,
    const uint32_t* __restrict__ colbits, const float* __restrict__ h,
    unsigned short* __restrict__ qtb, float* __restrict__ out, int last) {
  __shared__ float muL[CC * CC];     // 4 KB
  __shared__ float Tf[64];
  __shared__ float S[64];
  __shared__ uint32_t qs[256][17];   // 17 KB (fresh Q, bf16 pairs)
  __shared__ float es[256][2];       // 2 KB
  __shared__ float part[4][64];      // 1 KB
  const int bid = blockIdx.x;
  const int b = bid >> 2, seg = bid & 3;
  const int t = threadIdx.x;
  for (int i = t; i < CC * CC; i += 256) muL[i] = mu[i];
  if (t < 64) {
    float s = 0.f;
    for (int p = 0; p < npart; p++) s += TpIn[((size_t)b * npart + p) * 64 + t];
    Tf[t] = s;
  }
  __syncthreads();
  if (t < 64) {
    const int k = t >> 5, c = t & 31;
    float ss = 0.f;
    #pragma unroll 8
    for (int d = 0; d < CC; d++) ss += Tf[k * 32 + d] * muL[d * 32 + c];
    S[t] = ((k == 0) ? kwp[0] : kwp[1]) * ss;
  }
  __syncthreads();
  const int n = seg * 256 + t;
  const int gid = b * NN + n;
  const float e0 = e2g[(size_t)gid * 2 + 0];
  const float e1 = e2g[(size_t)gid * 2 + 1];
  es[t][0] = e0; es[t][1] = e1;
  float lg[CC];
  {
    const float4* ur = (const float4*)(unary + (size_t)gid * CC);
    const float4* S0 = (const float4*)S;
    const float4* S1 = (const float4*)(S + 32);
    #pragma unroll
    for (int c4 = 0; c4 < 8; c4++) {
      float4 uv = ur[c4], s0 = S0[c4], s1 = S1[c4];
      lg[c4*4]   = uv.x + e0 * s0.x + e1 * s1.x;
      lg[c4*4+1] = uv.y + e0 * s0.y + e1 * s1.y;
      lg[c4*4+2] = uv.z + e0 * s0.z + e1 * s1.z;
      lg[c4*4+3] = uv.w + e0 * s0.w + e1 * s1.w;
    }
  }
  const int zc = zcnt[gid];
  if (zc > 0) {
    const float kw0 = kwp[0], kw1 = kwp[1];
    if (zc <= ZCAP) {
      for (int z = 0; z < zc; z++) {
        const int j = zidx[(size_t)gid * ZCAP + z];
        const float w = kw0 * e0 * e2g[((size_t)b * NN + j) * 2 + 0]
                      + kw1 * e1 * e2g[((size_t)b * NN + j) * 2 + 1];
        const unsigned short* qj = Qprev + ((size_t)b * NN + j) * CC;
        for (int d = 0; d < CC; d++) {
          const float wq = w * b2f(qj[d]);
          #pragma unroll 8
          for (int c = 0; c < CC; c++) lg[c] -= wq * muL[d * CC + c];
        }
      }
    } else {  // dense fallback (never triggers for this input)
      const uint32_t* rbi = rowbits + (size_t)gid * 32;
      for (int j = 0; j < NN; j++) {
        uint32_t m = 0;
        const uint32_t* cbj = colbits + ((size_t)b * NN + j) * 32;
        for (int w32 = 0; w32 < 32; w32++) m |= rbi[w32] & cbj[w32];
        if (m == 0) {
          const float kw0b = kwp[0], kw1b = kwp[1];
          const float w = kw0b * e0 * e2g[((size_t)b * NN + j) * 2 + 0]
                        + kw1b * e1 * e2g[((size_t)b * NN + j) * 2 + 1];
          const unsigned short* qj = Qprev + ((size_t)b * NN + j) * CC;
          for (int d = 0; d < CC; d++) {
            const float wq = w * b2f(qj[d]);
            #pragma unroll 8
            for (int c = 0; c < CC; c++) lg[c] -= wq * muL[d * CC + c];
          }
        }
      }
    }
  }
  float mx = lg[0];
  #pragma unroll
  for (int c = 1; c < CC; c++) mx = fmaxf(mx, lg[c]);
  float ss = 0.f;
  #pragma unroll
  for (int c = 0; c < CC; c++) { lg[c] = __expf((lg[c] - mx) * 2.0f); ss += lg[c]; }
  const float inv = 1.f / ss;
  uint32_t pk[16];
  #pragma unroll
  for (int d2 = 0; d2 < 16; d2++) {
    pk[d2] = (uint32_t)f2b(lg[2*d2] * inv) | ((uint32_t)f2b(lg[2*d2+1] * inv) << 16);
    qs[t][d2] = pk[d2];
  }
  if (!last) {
    uint32_t* qn = (uint32_t*)(Qnext + (size_t)gid * CC);
    #pragma unroll
    for (int d2 = 0; d2 < 16; d2++) qn[d2] = pk[d2];
  }
  __syncthreads();
  if (!last) {
    // own-shard T-partial from fresh Q (k_titer pattern; wave-uniform j rows)
    const int kd = t & 63, d = t & 31, k = (t >> 5) & 1, sub = t >> 6;
    float s = 0.f;
    #pragma unroll 4
    for (int jj = 0; jj < 64; jj++) {
      const int j = sub * 64 + jj;
      const uint32_t w = qs[j][d >> 1];
      s += es[j][k] * ((d & 1) ? b2f_hi(w) : b2f_lo(w));
    }
    part[sub][kd] = s;
    __syncthreads();
    if (t < 64)
      TpOut[((size_t)b * 4 + seg) * 64 + t] = part[0][t] + part[1][t] + part[2][t] + part[3][t];
  } else {
    // qtb c-major (coalesced per c across the wave)
    #pragma unroll
    for (int c = 0; c < CC; c++) {
      const uint32_t w = pk[c >> 1];
      qtb[((size_t)b * CC + c) * NN + n] =
          (unsigned short)((c & 1) ? (w >> 16) : (w & 0xFFFFu));
    }
    // x_pooled partial for own 256-node shard
    const int hh = t & 63, cg = t >> 6;
    float acc[8] = {0, 0, 0, 0, 0, 0, 0, 0};
    for (int jj = 0; jj < 256; jj++) {
      const int j = seg * 256 + jj;
      const float hv = h[((size_t)b * NN + j) * HH + hh];
      #pragma unroll
      for (int w = 0; w < 4; w++) {
        const uint32_t q2 = qs[jj][cg * 4 + w];
        acc[2*w]     += b2f_lo(q2) * hv;
        acc[2*w + 1] += b2f_hi(q2) * hv;
      }
    }
    #pragma unroll
    for (int k2 = 0; k2 < 8; k2++)
      atomicAdd(&out[((size_t)b * CC + cg * 8 + k2) * HH + hh], acc[k2]);
  }
}

// ---------------------------------------------------------------------------
// k_adjqp: adjQ = A @ Q (MFMA from rowbits + qtb), then adj_pooled partials
// via LDS tiles. grid = B*16.
// ---------------------------------------------------------------------------
__global__ __launch_bounds__(256) void k_adjqp(const uint32_t* __restrict__ rowbits,
    const unsigned short* __restrict__ qtb, float* __restrict__ out) {
  __shared__ float adjL[64][33];
  __shared__ float qL[64][32];
  const int bid = blockIdx.x;
  const int b = bid >> 4;
  const int m0 = (bid & 15) * 64;
  const int t = threadIdx.x, wv = t >> 6, lane = t & 63, l15 = lane & 15, q = lane >> 4;
  const int mb = m0 + wv * 16;
  floatx4 acc[2];
  acc[0] = zf4(); acc[1] = zf4();
  const uint32_t* rbrow = rowbits + ((size_t)b * NN + mb + l15) * 32;
  for (int k0 = 0; k0 < NN; k0 += 32) {
    uint32_t sh = rbrow[k0 >> 5] >> (q * 8);
    short8 af;
    #pragma unroll
    for (int jj = 0; jj < 8; jj++)
      af[jj] = (short)(((sh >> jj) & 1u) ? 0x3F80 : 0);
    #pragma unroll
    for (int u = 0; u < 2; u++) {
      short8 bf = *(const short8*)(qtb + ((size_t)b * CC + u * 16 + l15) * NN + k0 + q * 8);
      acc[u] = __builtin_amdgcn_mfma_f32_16x16x32_bf16(af, bf, acc[u], 0, 0, 0);
    }
  }
  #pragma unroll
  for (int r = 0; r < 4; r++)
    #pragma unroll
    for (int u = 0; u < 2; u++)
      adjL[wv * 16 + q * 4 + r][u * 16 + l15] = acc[u][r];
  #pragma unroll
  for (int x = 0; x < 8; x++) {
    const int idx = x * 256 + t;
    const int i = idx & 63, c = idx >> 6;
    qL[i][c] = b2f(qtb[((size_t)b * CC + c) * NN + m0 + i]);
  }
  __syncthreads();
  const int d = t & 31, cg = t >> 5;
  float a2[4] = {0, 0, 0, 0};
  for (int i = 0; i < 64; i++) {
    const float av = adjL[i][d];
    #pragma unroll
    for (int k = 0; k < 4; k++) a2[k] += qL[i][cg * 4 + k] * av;
  }
  #pragma unroll
  for (int k = 0; k < 4; k++)
    atomicAdd(&out[(size_t)NB * CC * HH + ((size_t)b * CC + cg * 4 + k) * CC + d], a2[k]);
}

// ---------------------------------------------------------------------------
extern "C" void kernel_launch(void* const* d_in, const int* in_sizes, int n_in,
                              void* d_out, int out_size, void* d_ws, size_t ws_size,
                              hipStream_t stream) {
  (void)in_sizes; (void)n_in; (void)out_size;
  const float* x      = (const float*)d_in[0];
  const int*   adj    = (const int*)d_in[1];
  const float* Wg     = (const float*)d_in[2];
  const float* bg     = (const float*)d_in[3];
  const float* Wu     = (const float*)d_in[4];
  const float* bu     = (const float*)d_in[5];
  const float* means  = (const float*)d_in[6];
  const float* scales = (const float*)d_in[7];
  const float* kw     = (const float*)d_in[8];
  const float* mu     = (const float*)d_in[9];

  char* ws = (char*)d_ws;
  size_t off = 0;
  auto alloc = [&](size_t bytes) { char* p = ws + off; off += (bytes + 255) & ~(size_t)255; return p; };
  uint32_t*       rbits = (uint32_t*)alloc((size_t)NB * NN * 32 * 4);
  uint32_t*       cbits = (uint32_t*)alloc((size_t)NB * NN * 32 * 4);
  float*          dinv  = (float*)alloc((size_t)NB * NN * 4);
  unsigned short* Wgt   = (unsigned short*)alloc((size_t)HH * FIN * 2);
  unsigned short* Wut   = (unsigned short*)alloc((size_t)CC * HH * 2);
  unsigned short* xs    = (unsigned short*)alloc((size_t)NB * NN * HH * 2);
  unsigned short* xst   = (unsigned short*)alloc((size_t)NB * HH * NN * 2);
  float*          h     = (float*)alloc((size_t)NB * NN * HH * 4);
  float*          e2    = (float*)alloc((size_t)NB * NN * 2 * 4);
  float*          unary = (float*)alloc((size_t)NB * NN * CC * 4);
  int*            zcnt  = (int*)alloc((size_t)NB * NN * 4);
  int*            zidx  = (int*)alloc((size_t)NB * NN * ZCAP * 4);
  unsigned short* Qa    = (unsigned short*)alloc((size_t)NB * NN * CC * 2);
  unsigned short* Qb    = (unsigned short*)alloc((size_t)NB * NN * CC * 2);
  unsigned short* qtb   = (unsigned short*)alloc((size_t)NB * CC * NN * 2);
  float*          Tp0   = (float*)alloc((size_t)NB * 16 * 64 * 4);
  float*          TpA   = (float*)alloc((size_t)NB * 4 * 64 * 4);
  float*          TpB   = (float*)alloc((size_t)NB * 4 * 64 * 4);
  if (off > ws_size) return;

  float* out = (float*)d_out;
  const int out_n = NB * CC * (HH + CC);

  k_wcvt <<<1, 256, 0, stream>>>(Wg, Wu, Wgt, Wut, out, out_n);
  k_bits <<<NB * NN / 4, 256, 0, stream>>>(adj, rbits, dinv, zcnt);
  k_cbits<<<NB * 8, 256, 0, stream>>>(rbits, cbits);
  k_zscan<<<NB * 8, 256, 0, stream>>>(rbits, cbits, zcnt, zidx);
  k_xw   <<<NB * 16, 256, 0, stream>>>(x, Wgt, dinv, xs, xst);
  k_gcnun<<<NB * 16, 256, 0, stream>>>(rbits, xst, xs, dinv, bg, means, scales,
                                       Wut, bu, h, e2, unary, Qa, Tp0);
  // 5 CRF iterations, 1 launch each: Tp0(16) -> TpA -> TpB -> TpA -> TpB(read only)
  unsigned short* qprev = Qa; unsigned short* qnext = Qb;
  const float* tin = Tp0; int npart = 16; float* tout = TpA;
  for (int it = 0; it < NITER; it++) {
    const int last = (it == NITER - 1) ? 1 : 0;
    k_supd2<<<NB * 4, 256, 0, stream>>>(unary, e2, tin, npart, mu, kw, zcnt, zidx,
                                        qprev, qnext, tout, rbits, cbits, h,
                                        qtb, out, last);
    unsigned short* tmpq = qprev; qprev = qnext; qnext = tmpq;
    tin = tout; npart = 4;
    tout = (tout == TpA) ? TpB : TpA;
  }
  k_adjqp<<<NB * 16, 256, 0, stream>>>(rbits, qtb, out);
}

// Round 10
// 392.861 us; speedup vs baseline: 1.1145x; 1.0669x over previous
//
#include <hip/hip_runtime.h>
#include <stdint.h>

#define NB  32     // B
#define NN  1024   // N
#define FIN 128
#define HH  64
#define CC  32
#define ZCAP 16
#define NITER 5

using short8  = __attribute__((ext_vector_type(8))) short;
using floatx4 = __attribute__((ext_vector_type(4))) float;

__device__ inline float b2f(unsigned short u) {
  union { uint32_t i; float f; } v; v.i = ((uint32_t)u) << 16; return v.f;
}
__device__ inline float b2f_lo(uint32_t w) {
  union { uint32_t i; float f; } v; v.i = w << 16; return v.f;
}
__device__ inline float b2f_hi(uint32_t w) {
  union { uint32_t i; float f; } v; v.i = w & 0xFFFF0000u; return v.f;
}
__device__ inline unsigned short f2b(float f) {
  union { uint32_t i; float f; } v; v.f = f;
  uint32_t r = v.i + 0x7FFFu + ((v.i >> 16) & 1u);
  return (unsigned short)(r >> 16);
}
__device__ inline floatx4 zf4() { floatx4 v = {0.f, 0.f, 0.f, 0.f}; return v; }

// ---------------------------------------------------------------------------
// k_bits: blocks [0, B*N/4): adj -> rowbits + dinv + zcnt=0 (one wave/row).
// Block B*N/4: weight transposes to bf16 + zero d_out (former k_wcvt).
// ---------------------------------------------------------------------------
__global__ __launch_bounds__(256) void k_bits(const int* __restrict__ adj,
    uint32_t* __restrict__ rowbits, float* __restrict__ dinv,
    int* __restrict__ zcnt, const float* __restrict__ Wg,
    const float* __restrict__ Wu, unsigned short* __restrict__ Wgt,
    unsigned short* __restrict__ Wut, float* __restrict__ out, int out_n) {
  const int t = threadIdx.x;
  if (blockIdx.x == NB * NN / 4) {   // wcvt block
    for (int idx = t; idx < HH * FIN; idx += 256) {
      int hh = idx >> 7, f = idx & 127;
      Wgt[idx] = f2b(Wg[f * HH + hh]);
    }
    for (int idx = t; idx < CC * HH; idx += 256) {
      int c = idx >> 6, f = idx & 63;
      Wut[idx] = f2b(Wu[f * CC + c]);
    }
    for (int idx = t; idx < out_n; idx += 256) out[idx] = 0.f;
    return;
  }
  __shared__ uint32_t rw[4][32];
  const int g = t >> 6, lane = t & 63;
  if (lane < 32) rw[g][lane] = 0u;
  __syncthreads();
  const size_t row = (size_t)blockIdx.x * 4 + g;
  int s = 0;
  #pragma unroll
  for (int rep = 0; rep < 4; rep++) {
    int4 a = ((const int4*)(adj + row * NN))[rep * 64 + lane];
    int b0 = (a.x != 0), b1 = (a.y != 0), b2 = (a.z != 0), b3 = (a.w != 0);
    uint32_t nib = ((uint32_t)(b0 | (b1 << 1) | (b2 << 2) | (b3 << 3))) << ((lane & 7) * 4);
    atomicOr(&rw[g][rep * 8 + (lane >> 3)], nib);
    s += b0 + b1 + b2 + b3;
  }
  #pragma unroll
  for (int m = 1; m < 64; m <<= 1) s += __shfl_xor(s, m, 64);
  __syncthreads();
  if (lane < 32) rowbits[row * 32 + lane] = rw[g][lane];
  if (lane == 0) { dinv[row] = rsqrtf((float)s + 1.0f); zcnt[row] = 0; }
}

// ---------------------------------------------------------------------------
// k_xwz: blocks [0, B*16): xs[n][h] = bf16(dinv_n*(x@Wg)) + xst transpose.
// blocks [B*16, 2*B*16): zscan2 — zero-mask rows of A^2 via neighbor-row
// bit-union with wave-vote early exit (replaces colbits + old zscan).
// ---------------------------------------------------------------------------
__global__ __launch_bounds__(256) void k_xwz(const float* __restrict__ x,
    const unsigned short* __restrict__ Wgt, const float* __restrict__ dinv,
    unsigned short* __restrict__ xs, unsigned short* __restrict__ xst,
    const uint32_t* __restrict__ rowbits, int* __restrict__ zcnt,
    int* __restrict__ zidx) {
  const int t = threadIdx.x;
  if (blockIdx.x >= NB * 16) {       // ---- zscan2 half ----
    const int zbid = blockIdx.x - NB * 16;
    const int b = zbid >> 4, i0 = (zbid & 15) * 64;
    const int wv = t >> 6, lane = t & 63, lw = lane & 31;
    for (int rep = 0; rep < 16; rep++) {   // 4 waves x 16 -> 64 nodes
      const int i = i0 + wv * 16 + rep;
      const uint32_t* rbi = rowbits + ((size_t)b * NN + i) * 32;
      uint32_t u = 0;
      int done = 0;
      for (int wi = 0; wi < 32 && !done; wi++) {
        uint32_t wb = rbi[wi];           // wave-uniform
        while (wb) {
          const int p = __ffs(wb) - 1;
          wb &= wb - 1;
          const int k = wi * 32 + p;
          u |= rowbits[((size_t)b * NN + k) * 32 + lw];
          if (__all(u == 0xFFFFFFFFu)) { done = 1; break; }
        }
      }
      if (!done && lane < 32) {          // uncovered j's (essentially never)
        uint32_t miss = ~u;
        while (miss) {
          const int p = __ffs(miss) - 1;
          miss &= miss - 1;
          const int j = lw * 32 + p;
          int old = atomicAdd(&zcnt[b * NN + i], 1);
          if (old < ZCAP) zidx[(size_t)(b * NN + i) * ZCAP + old] = j;
        }
      }
    }
    return;
  }
  // ---- xw half ----
  const int bid = blockIdx.x;
  const int b = bid >> 4;
  const int m0 = (bid & 15) * 64;
  const int wv = t >> 6, lane = t & 63, l15 = lane & 15, q = lane >> 4;
  const int mb = m0 + wv * 16;
  floatx4 acc[4];
  #pragma unroll
  for (int u = 0; u < 4; u++) acc[u] = zf4();
  #pragma unroll
  for (int k0 = 0; k0 < FIN; k0 += 32) {
    const float4* xp = (const float4*)(x + ((size_t)b * NN + mb + l15) * FIN + k0 + q * 8);
    float4 a0 = xp[0], a1 = xp[1];
    short8 af;
    af[0] = (short)f2b(a0.x); af[1] = (short)f2b(a0.y);
    af[2] = (short)f2b(a0.z); af[3] = (short)f2b(a0.w);
    af[4] = (short)f2b(a1.x); af[5] = (short)f2b(a1.y);
    af[6] = (short)f2b(a1.z); af[7] = (short)f2b(a1.w);
    #pragma unroll
    for (int u = 0; u < 4; u++) {
      short8 bf = *(const short8*)(Wgt + (u * 16 + l15) * FIN + k0 + q * 8);
      acc[u] = __builtin_amdgcn_mfma_f32_16x16x32_bf16(af, bf, acc[u], 0, 0, 0);
    }
  }
  #pragma unroll
  for (int r = 0; r < 4; r++) {
    const int i = mb + q * 4 + r;
    const float dv = dinv[b * NN + i];
    #pragma unroll
    for (int u = 0; u < 4; u++) {
      const int c = u * 16 + l15;
      unsigned short bv = f2b(dv * acc[u][r]);
      xs[((size_t)b * NN + i) * HH + c] = bv;
      xst[((size_t)b * HH + c) * NN + i] = bv;
    }
  }
}

// ---------------------------------------------------------------------------
// k_gcnun: h = relu(dinv_i*(A@xs + xs_i) + bg); fused e2, unary = h@Wu+bu,
// Q0 = softmax(unary) (bf16 row-major) and Tpart0 (16 partials/batch).
// grid = B*16, 256 thr
// ---------------------------------------------------------------------------
__global__ __launch_bounds__(256) void k_gcnun(const uint32_t* __restrict__ rowbits,
    const unsigned short* __restrict__ xst, const unsigned short* __restrict__ xs,
    const float* __restrict__ dinv, const float* __restrict__ bg,
    const float* __restrict__ means, const float* __restrict__ scales,
    const unsigned short* __restrict__ Wut, const float* __restrict__ bu,
    float* __restrict__ h, float* __restrict__ e2, float* __restrict__ unary,
    unsigned short* __restrict__ Q0, float* __restrict__ Tp0) {
  __shared__ unsigned short hsh[4][16][72];   // 9 KB
  __shared__ float Qs0[64][33];               // 8.4 KB
  __shared__ float es0[64][2];
  const int bid = blockIdx.x;
  const int b = bid >> 4, blk = bid & 15;
  const int m0 = blk * 64;
  const int t = threadIdx.x, wv = t >> 6, lane = t & 63, l15 = lane & 15, q = lane >> 4;
  const int mb = m0 + wv * 16;
  floatx4 acc[4];
  #pragma unroll
  for (int u = 0; u < 4; u++) acc[u] = zf4();
  const uint32_t* rbrow = rowbits + ((size_t)b * NN + mb + l15) * 32;
  for (int k0 = 0; k0 < NN; k0 += 32) {
    uint32_t sh = rbrow[k0 >> 5] >> (q * 8);
    short8 af;
    #pragma unroll
    for (int jj = 0; jj < 8; jj++)
      af[jj] = (short)(((sh >> jj) & 1u) ? 0x3F80 : 0);
    #pragma unroll
    for (int u = 0; u < 4; u++) {
      short8 bf = *(const short8*)(xst + ((size_t)b * HH + u * 16 + l15) * NN + k0 + q * 8);
      acc[u] = __builtin_amdgcn_mfma_f32_16x16x32_bf16(af, bf, acc[u], 0, 0, 0);
    }
  }
  float bgc[4], mn0[4], mn1[4], is0[4], is1[4];
  #pragma unroll
  for (int u = 0; u < 4; u++) {
    const int c = u * 16 + l15;
    bgc[u] = bg[c];
    mn0[u] = means[c];        is0[u] = 1.0f / scales[c];
    mn1[u] = means[HH + c];   is1[u] = 1.0f / scales[HH + c];
  }
  #pragma unroll
  for (int r = 0; r < 4; r++) {
    const int i = mb + q * 4 + r;
    const float dv = dinv[b * NN + i];
    float dd0 = 0.f, dd1 = 0.f;
    #pragma unroll
    for (int u = 0; u < 4; u++) {
      const int c = u * 16 + l15;
      float xsv = b2f(xs[((size_t)b * NN + i) * HH + c]);
      float v = dv * (acc[u][r] + xsv) + bgc[u];
      v = v > 0.f ? v : 0.f;
      h[((size_t)b * NN + i) * HH + c] = v;
      unsigned short hb = f2b(v);
      hsh[wv][q * 4 + r][c] = hb;
      float vb = b2f(hb);
      float t0 = (vb - mn0[u]) * is0[u]; dd0 += t0 * t0;
      float t1 = (vb - mn1[u]) * is1[u]; dd1 += t1 * t1;
    }
    #pragma unroll
    for (int m = 1; m < 16; m <<= 1) {
      dd0 += __shfl_xor(dd0, m, 64);
      dd1 += __shfl_xor(dd1, m, 64);
    }
    if (l15 == 0) {
      float ev0 = __expf(-dd0), ev1 = __expf(-dd1);
      e2[((size_t)b * NN + i) * 2 + 0] = ev0;
      e2[((size_t)b * NN + i) * 2 + 1] = ev1;
      es0[wv * 16 + q * 4 + r][0] = ev0;
      es0[wv * 16 + q * 4 + r][1] = ev1;
    }
  }
  floatx4 uacc[2];
  uacc[0] = zf4(); uacc[1] = zf4();
  #pragma unroll
  for (int k0 = 0; k0 < HH; k0 += 32) {
    short8 af = *(const short8*)&hsh[wv][l15][k0 + q * 8];
    #pragma unroll
    for (int u = 0; u < 2; u++) {
      short8 bf = *(const short8*)(Wut + (u * 16 + l15) * HH + k0 + q * 8);
      uacc[u] = __builtin_amdgcn_mfma_f32_16x16x32_bf16(af, bf, uacc[u], 0, 0, 0);
    }
  }
  const float bu0 = bu[l15], bu1 = bu[16 + l15];
  #pragma unroll
  for (int r = 0; r < 4; r++) {
    const int i = mb + q * 4 + r;
    const int iloc = wv * 16 + q * 4 + r;
    float a0 = uacc[0][r] + bu0;
    float a1 = uacc[1][r] + bu1;
    unary[((size_t)b * NN + i) * CC + l15] = a0;
    unary[((size_t)b * NN + i) * CC + 16 + l15] = a1;
    float mx = fmaxf(a0, a1);
    #pragma unroll
    for (int m = 1; m < 16; m <<= 1) mx = fmaxf(mx, __shfl_xor(mx, m, 64));
    float x0 = __expf(a0 - mx), x1 = __expf(a1 - mx);
    float s = x0 + x1;
    #pragma unroll
    for (int m = 1; m < 16; m <<= 1) s += __shfl_xor(s, m, 64);
    float inv = 1.f / s;
    float q0v = x0 * inv, q1v = x1 * inv;
    Q0[((size_t)b * NN + i) * CC + l15] = f2b(q0v);
    Q0[((size_t)b * NN + i) * CC + 16 + l15] = f2b(q1v);
    Qs0[iloc][l15] = q0v;
    Qs0[iloc][16 + l15] = q1v;
  }
  __syncthreads();
  if (t < 64) {
    const int k = t >> 5, d = t & 31;
    float s = 0.f;
    #pragma unroll 8
    for (int i = 0; i < 64; i++) s += es0[i][k] * Qs0[i][d];
    Tp0[((size_t)b * 16 + blk) * 64 + t] = s;
  }
}

// ---------------------------------------------------------------------------
// k_supd2: one CRF iteration. grid = B*4, 256 thr, 1 node/thread.
// Sums npart T-partials -> S; update own 256 nodes; writes own T-partial for
// next iter. Last iter: qtb (c-major) + x_pooled partials.
// ---------------------------------------------------------------------------
__global__ __launch_bounds__(256) void k_supd2(const float* __restrict__ unary,
    const float* __restrict__ e2g, const float* __restrict__ TpIn, int npart,
    const float* __restrict__ mu, const float* __restrict__ kwp,
    const int* __restrict__ zcnt, const int* __restrict__ zidx,
    const unsigned short* __restrict__ Qprev, unsigned short* __restrict__ Qnext,
    float* __restrict__ TpOut, const uint32_t* __restrict__ rowbits,
    const float* __restrict__ h, unsigned short* __restrict__ qtb,
    float* __restrict__ out, int last) {
  __shared__ float muL[CC * CC];
  __shared__ float Tf[64];
  __shared__ float S[64];
  __shared__ uint32_t qs[256][17];
  __shared__ float es[256][2];
  __shared__ float part[4][64];
  const int bid = blockIdx.x;
  const int b = bid >> 2, seg = bid & 3;
  const int t = threadIdx.x;
  for (int i = t; i < CC * CC; i += 256) muL[i] = mu[i];
  if (t < 64) {
    float s = 0.f;
    for (int p = 0; p < npart; p++) s += TpIn[((size_t)b * npart + p) * 64 + t];
    Tf[t] = s;
  }
  __syncthreads();
  if (t < 64) {
    const int k = t >> 5, c = t & 31;
    float ss = 0.f;
    #pragma unroll 8
    for (int d = 0; d < CC; d++) ss += Tf[k * 32 + d] * muL[d * 32 + c];
    S[t] = ((k == 0) ? kwp[0] : kwp[1]) * ss;
  }
  __syncthreads();
  const int n = seg * 256 + t;
  const int gid = b * NN + n;
  const float e0 = e2g[(size_t)gid * 2 + 0];
  const float e1 = e2g[(size_t)gid * 2 + 1];
  es[t][0] = e0; es[t][1] = e1;
  float lg[CC];
  {
    const float4* ur = (const float4*)(unary + (size_t)gid * CC);
    const float4* S0 = (const float4*)S;
    const float4* S1 = (const float4*)(S + 32);
    #pragma unroll
    for (int c4 = 0; c4 < 8; c4++) {
      float4 uv = ur[c4], s0 = S0[c4], s1 = S1[c4];
      lg[c4*4]   = uv.x + e0 * s0.x + e1 * s1.x;
      lg[c4*4+1] = uv.y + e0 * s0.y + e1 * s1.y;
      lg[c4*4+2] = uv.z + e0 * s0.z + e1 * s1.z;
      lg[c4*4+3] = uv.w + e0 * s0.w + e1 * s1.w;
    }
  }
  const int zc = zcnt[gid];
  if (zc > 0) {
    const float kw0 = kwp[0], kw1 = kwp[1];
    if (zc <= ZCAP) {
      for (int z = 0; z < zc; z++) {
        const int j = zidx[(size_t)gid * ZCAP + z];
        const float w = kw0 * e0 * e2g[((size_t)b * NN + j) * 2 + 0]
                      + kw1 * e1 * e2g[((size_t)b * NN + j) * 2 + 1];
        const unsigned short* qj = Qprev + ((size_t)b * NN + j) * CC;
        for (int d = 0; d < CC; d++) {
          const float wq = w * b2f(qj[d]);
          #pragma unroll 8
          for (int c = 0; c < CC; c++) lg[c] -= wq * muL[d * CC + c];
        }
      }
    } else {  // colbits-free exact fallback (never triggers for this input)
      const uint32_t* rbi = rowbits + (size_t)gid * 32;
      for (int j = 0; j < NN; j++) {
        int found = 0;
        for (int wi = 0; wi < 32 && !found; wi++) {
          uint32_t wb = rbi[wi];
          while (wb) {
            const int p = __ffs(wb) - 1;
            wb &= wb - 1;
            const int k = wi * 32 + p;
            if ((rowbits[((size_t)b * NN + k) * 32 + (j >> 5)] >> (j & 31)) & 1u) {
              found = 1; break;
            }
          }
        }
        if (!found) {
          const float w = kw0 * e0 * e2g[((size_t)b * NN + j) * 2 + 0]
                        + kw1 * e1 * e2g[((size_t)b * NN + j) * 2 + 1];
          const unsigned short* qj = Qprev + ((size_t)b * NN + j) * CC;
          for (int d = 0; d < CC; d++) {
            const float wq = w * b2f(qj[d]);
            #pragma unroll 8
            for (int c = 0; c < CC; c++) lg[c] -= wq * muL[d * CC + c];
          }
        }
      }
    }
  }
  float mx = lg[0];
  #pragma unroll
  for (int c = 1; c < CC; c++) mx = fmaxf(mx, lg[c]);
  float ss = 0.f;
  #pragma unroll
  for (int c = 0; c < CC; c++) { lg[c] = __expf((lg[c] - mx) * 2.0f); ss += lg[c]; }
  const float inv = 1.f / ss;
  uint32_t pk[16];
  #pragma unroll
  for (int d2 = 0; d2 < 16; d2++) {
    pk[d2] = (uint32_t)f2b(lg[2*d2] * inv) | ((uint32_t)f2b(lg[2*d2+1] * inv) << 16);
    qs[t][d2] = pk[d2];
  }
  if (!last) {
    uint32_t* qn = (uint32_t*)(Qnext + (size_t)gid * CC);
    #pragma unroll
    for (int d2 = 0; d2 < 16; d2++) qn[d2] = pk[d2];
  }
  __syncthreads();
  if (!last) {
    const int kd = t & 63, d = t & 31, k = (t >> 5) & 1, sub = t >> 6;
    float s = 0.f;
    #pragma unroll 4
    for (int jj = 0; jj < 64; jj++) {
      const int j = sub * 64 + jj;
      const uint32_t w = qs[j][d >> 1];
      s += es[j][k] * ((d & 1) ? b2f_hi(w) : b2f_lo(w));
    }
    part[sub][kd] = s;
    __syncthreads();
    if (t < 64)
      TpOut[((size_t)b * 4 + seg) * 64 + t] = part[0][t] + part[1][t] + part[2][t] + part[3][t];
  } else {
    #pragma unroll
    for (int c = 0; c < CC; c++) {
      const uint32_t w = pk[c >> 1];
      qtb[((size_t)b * CC + c) * NN + n] =
          (unsigned short)((c & 1) ? (w >> 16) : (w & 0xFFFFu));
    }
    const int hh = t & 63, cg = t >> 6;
    float acc[8] = {0, 0, 0, 0, 0, 0, 0, 0};
    for (int jj = 0; jj < 256; jj++) {
      const int j = seg * 256 + jj;
      const float hv = h[((size_t)b * NN + j) * HH + hh];
      #pragma unroll
      for (int w = 0; w < 4; w++) {
        const uint32_t q2 = qs[jj][cg * 4 + w];
        acc[2*w]     += b2f_lo(q2) * hv;
        acc[2*w + 1] += b2f_hi(q2) * hv;
      }
    }
    #pragma unroll
    for (int k2 = 0; k2 < 8; k2++)
      atomicAdd(&out[((size_t)b * CC + cg * 8 + k2) * HH + hh], acc[k2]);
  }
}

// ---------------------------------------------------------------------------
// k_adjqp: adjQ = A @ Q (MFMA from rowbits + qtb), then adj_pooled partials
// via LDS tiles. grid = B*16.
// ---------------------------------------------------------------------------
__global__ __launch_bounds__(256) void k_adjqp(const uint32_t* __restrict__ rowbits,
    const unsigned short* __restrict__ qtb, float* __restrict__ out) {
  __shared__ float adjL[64][33];
  __shared__ float qL[64][32];
  const int bid = blockIdx.x;
  const int b = bid >> 4;
  const int m0 = (bid & 15) * 64;
  const int t = threadIdx.x, wv = t >> 6, lane = t & 63, l15 = lane & 15, q = lane >> 4;
  const int mb = m0 + wv * 16;
  floatx4 acc[2];
  acc[0] = zf4(); acc[1] = zf4();
  const uint32_t* rbrow = rowbits + ((size_t)b * NN + mb + l15) * 32;
  for (int k0 = 0; k0 < NN; k0 += 32) {
    uint32_t sh = rbrow[k0 >> 5] >> (q * 8);
    short8 af;
    #pragma unroll
    for (int jj = 0; jj < 8; jj++)
      af[jj] = (short)(((sh >> jj) & 1u) ? 0x3F80 : 0);
    #pragma unroll
    for (int u = 0; u < 2; u++) {
      short8 bf = *(const short8*)(qtb + ((size_t)b * CC + u * 16 + l15) * NN + k0 + q * 8);
      acc[u] = __builtin_amdgcn_mfma_f32_16x16x32_bf16(af, bf, acc[u], 0, 0, 0);
    }
  }
  #pragma unroll
  for (int r = 0; r < 4; r++)
    #pragma unroll
    for (int u = 0; u < 2; u++)
      adjL[wv * 16 + q * 4 + r][u * 16 + l15] = acc[u][r];
  #pragma unroll
  for (int x = 0; x < 8; x++) {
    const int idx = x * 256 + t;
    const int i = idx & 63, c = idx >> 6;
    qL[i][c] = b2f(qtb[((size_t)b * CC + c) * NN + m0 + i]);
  }
  __syncthreads();
  const int d = t & 31, cg = t >> 5;
  float a2[4] = {0, 0, 0, 0};
  for (int i = 0; i < 64; i++) {
    const float av = adjL[i][d];
    #pragma unroll
    for (int k = 0; k < 4; k++) a2[k] += qL[i][cg * 4 + k] * av;
  }
  #pragma unroll
  for (int k = 0; k < 4; k++)
    atomicAdd(&out[(size_t)NB * CC * HH + ((size_t)b * CC + cg * 4 + k) * CC + d], a2[k]);
}

// ---------------------------------------------------------------------------
extern "C" void kernel_launch(void* const* d_in, const int* in_sizes, int n_in,
                              void* d_out, int out_size, void* d_ws, size_t ws_size,
                              hipStream_t stream) {
  (void)in_sizes; (void)n_in; (void)out_size;
  const float* x      = (const float*)d_in[0];
  const int*   adj    = (const int*)d_in[1];
  const float* Wg     = (const float*)d_in[2];
  const float* bg     = (const float*)d_in[3];
  const float* Wu     = (const float*)d_in[4];
  const float* bu     = (const float*)d_in[5];
  const float* means  = (const float*)d_in[6];
  const float* scales = (const float*)d_in[7];
  const float* kw     = (const float*)d_in[8];
  const float* mu     = (const float*)d_in[9];

  char* ws = (char*)d_ws;
  size_t off = 0;
  auto alloc = [&](size_t bytes) { char* p = ws + off; off += (bytes + 255) & ~(size_t)255; return p; };
  uint32_t*       rbits = (uint32_t*)alloc((size_t)NB * NN * 32 * 4);
  float*          dinv  = (float*)alloc((size_t)NB * NN * 4);
  unsigned short* Wgt   = (unsigned short*)alloc((size_t)HH * FIN * 2);
  unsigned short* Wut   = (unsigned short*)alloc((size_t)CC * HH * 2);
  unsigned short* xs    = (unsigned short*)alloc((size_t)NB * NN * HH * 2);
  unsigned short* xst   = (unsigned short*)alloc((size_t)NB * HH * NN * 2);
  float*          h     = (float*)alloc((size_t)NB * NN * HH * 4);
  float*          e2    = (float*)alloc((size_t)NB * NN * 2 * 4);
  float*          unary = (float*)alloc((size_t)NB * NN * CC * 4);
  int*            zcnt  = (int*)alloc((size_t)NB * NN * 4);
  int*            zidx  = (int*)alloc((size_t)NB * NN * ZCAP * 4);
  unsigned short* Qa    = (unsigned short*)alloc((size_t)NB * NN * CC * 2);
  unsigned short* Qb    = (unsigned short*)alloc((size_t)NB * NN * CC * 2);
  unsigned short* qtb   = (unsigned short*)alloc((size_t)NB * CC * NN * 2);
  float*          Tp0   = (float*)alloc((size_t)NB * 16 * 64 * 4);
  float*          TpA   = (float*)alloc((size_t)NB * 4 * 64 * 4);
  float*          TpB   = (float*)alloc((size_t)NB * 4 * 64 * 4);
  if (off > ws_size) return;

  float* out = (float*)d_out;
  const int out_n = NB * CC * (HH + CC);

  k_bits <<<NB * NN / 4 + 1, 256, 0, stream>>>(adj, rbits, dinv, zcnt,
                                               Wg, Wu, Wgt, Wut, out, out_n);
  k_xwz  <<<NB * 32, 256, 0, stream>>>(x, Wgt, dinv, xs, xst, rbits, zcnt, zidx);
  k_gcnun<<<NB * 16, 256, 0, stream>>>(rbits, xst, xs, dinv, bg, means, scales,
                                       Wut, bu, h, e2, unary, Qa, Tp0);
  unsigned short* qprev = Qa; unsigned short* qnext = Qb;
  const float* tin = Tp0; int npart = 16; float* tout = TpA;
  for (int it = 0; it < NITER; it++) {
    const int last = (it == NITER - 1) ? 1 : 0;
    k_supd2<<<NB * 4, 256, 0, stream>>>(unary, e2, tin, npart, mu, kw, zcnt, zidx,
                                        qprev, qnext, tout, rbits, h, qtb, out, last);
    unsigned short* tmpq = qprev; qprev = qnext; qnext = tmpq;
    tin = tout; npart = 4;
    tout = (tout == TpA) ? TpB : TpA;
  }
  k_adjqp<<<NB * 16, 256, 0, stream>>>(rbits, qtb, out);
}